// Round 10
// baseline (1148.746 us; speedup 1.0000x reference)
//
#include <hip/hip_runtime.h>
#include <hip/hip_bf16.h>

#define N_NODES 50000
#define N_EDGES 800000
#define D 128
#define N_ETYPES 4
#define N_STEPS 8
#define B_GRAPHS 50
#define HID 256
#define POOL_SPLIT 16
#define N4 (N_NODES * N_ETYPES)          // 200000 per-(node,type) segments
#define SCAN_B4 ((N4 + 255) / 256)       // 782

typedef __attribute__((ext_vector_type(8))) short short8;
typedef __attribute__((ext_vector_type(4))) float f32x4;
typedef __attribute__((ext_vector_type(4))) unsigned uint4v;
typedef __attribute__((ext_vector_type(4))) int int4v;

static __device__ __forceinline__ unsigned short f2bf(float f) {
    union { float f; unsigned u; } v; v.f = f;
    unsigned r = v.u + 0x7FFF + ((v.u >> 16) & 1);
    return (unsigned short)(r >> 16);
}
static __device__ __forceinline__ unsigned pk2(float a, float b) {
    return (unsigned)f2bf(a) | ((unsigned)f2bf(b) << 16);
}
static __device__ __forceinline__ float bf2f_u(unsigned s) {  // low 16 bits
    union { unsigned u; float f; } v; v.u = s << 16;
    return v.f;
}
static __device__ __forceinline__ float bflo(unsigned x) {
    union { unsigned u; float f; } v; v.u = x << 16;
    return v.f;
}
static __device__ __forceinline__ float bfhi(unsigned x) {
    union { unsigned u; float f; } v; v.u = x & 0xFFFF0000u;
    return v.f;
}
static __device__ __forceinline__ float fsigmoid(float x) {
    return 1.f / (1.f + __expf(-x));
}
static __device__ __forceinline__ float ftanh(float x) {
    return 2.f / (1.f + __expf(-2.f * x)) - 1.f;
}

// ---------------- init: h_bf = bf16(node_features) ----------------
__global__ void k_init_h(const float* __restrict__ nf, unsigned short* __restrict__ hbf) {
    int i = blockIdx.x * blockDim.x + threadIdx.x;
    if (i < N_NODES * D) hbf[i] = f2bf(nf[i]);
}

// ---------------- CSR build over (dst, type) segments ----------------
__global__ void k_hist(const int* __restrict__ dst, const int* __restrict__ et,
                       int* __restrict__ deg4) {
    int e = blockIdx.x * blockDim.x + threadIdx.x;
    if (e < N_EDGES) atomicAdd(&deg4[dst[e] * 4 + et[e]], 1);
}

__global__ __launch_bounds__(256) void k_scan1(const int* __restrict__ deg4,
                                               int* __restrict__ bsum) {
    __shared__ int tmp[256];
    int t = threadIdx.x;
    int i = blockIdx.x * 256 + t;
    tmp[t] = (i < N4) ? deg4[i] : 0;
    __syncthreads();
    for (int s = 128; s > 0; s >>= 1) {
        if (t < s) tmp[t] += tmp[t + s];
        __syncthreads();
    }
    if (t == 0) bsum[blockIdx.x] = tmp[0];
}

__global__ __launch_bounds__(1024) void k_scan2(const int* __restrict__ bsum,
                                                int* __restrict__ bpfx,
                                                int* __restrict__ rowptr4) {
    __shared__ int part[1024];
    int t = threadIdx.x;
    int v = (t < SCAN_B4) ? bsum[t] : 0;
    part[t] = v;
    __syncthreads();
    for (int off = 1; off < 1024; off <<= 1) {
        int u = (t >= off) ? part[t - off] : 0;
        __syncthreads();
        part[t] += u;
        __syncthreads();
    }
    if (t < SCAN_B4) bpfx[t] = part[t] - v;  // exclusive
    if (t == SCAN_B4 - 1) rowptr4[N4] = part[t];  // = N_EDGES
}

__global__ __launch_bounds__(256) void k_scan3(const int* __restrict__ deg4,
                                               const int* __restrict__ bpfx,
                                               int* __restrict__ rowptr4,
                                               int* __restrict__ cursor4) {
    __shared__ int part[256];
    int t = threadIdx.x;
    int i = blockIdx.x * 256 + t;
    int v = (i < N4) ? deg4[i] : 0;
    part[t] = v;
    __syncthreads();
    for (int off = 1; off < 256; off <<= 1) {
        int u = (t >= off) ? part[t - off] : 0;
        __syncthreads();
        part[t] += u;
        __syncthreads();
    }
    if (i < N4) {
        int rp = bpfx[blockIdx.x] + part[t] - v;
        rowptr4[i] = rp;
        cursor4[i] = rp;
    }
}

// epack[slot] = src * 256 (pre-scaled byte offset into h rows)
__global__ void k_fill(const int* __restrict__ src, const int* __restrict__ dst,
                       const int* __restrict__ et, int* __restrict__ cursor4,
                       int* __restrict__ epack) {
    int e = blockIdx.x * blockDim.x + threadIdx.x;
    if (e < N_EDGES) {
        int slot = atomicAdd(&cursor4[dst[e] * 4 + et[e]], 1);
        epack[slot] = src[e] << 8;
    }
}

// ---------------- weight pre-pack into MFMA B-fragment layouts (bf16) --------
__global__ void k_pack(const float* __restrict__ Wmsg, const float* __restrict__ Wih,
                       const float* __restrict__ Whh, unsigned short* __restrict__ Pmsg,
                       unsigned short* __restrict__ Pih, unsigned short* __restrict__ Phh) {
    int bt = blockIdx.x;  // 0..319
    int l = threadIdx.x;  // 0..63
    if (bt < 128) {  // Pmsg frag f = bt ; f = nt*16 + kc
        int nt = bt >> 4, kc = bt & 15;
        int n = nt * 16 + (l & 15);
        unsigned short* out = Pmsg + (((size_t)bt * 64 + l) * 8);
#pragma unroll
        for (int i = 0; i < 8; ++i) {
            int k = kc * 32 + ((l >> 4) << 3) + i;
            out[i] = f2bf(Wmsg[(size_t)(k >> 7) * (D * D) + (k & 127) * D + n]);
        }
        return;
    }
    const float* src;
    unsigned short* dstp;
    int id;
    if (bt < 224) { id = bt - 128; src = Wih; dstp = Pih; }
    else          { id = bt - 224; src = Whh; dstp = Phh; }
    int nt = id >> 2, c = id & 3;
    int n = nt * 16 + (l & 15);
    unsigned short* out = dstp + (((size_t)(nt * 4 + c) * 64 + l) * 8);
#pragma unroll
    for (int i = 0; i < 8; ++i) {
        int k = c * 32 + ((l >> 4) << 3) + i;
        out[i] = f2bf(src[n * D + k]);
    }
}

// ---------------- tiny gate-bias table: gb4[col] = {br, bz, bin, bhn} -------
__global__ void k_pack_bias(const float* __restrict__ bih, const float* __restrict__ bhh,
                            float4* __restrict__ gb4) {
    int c = threadIdx.x;  // 0..127
    float4 g;
    g.x = bih[c] + bhh[c];
    g.y = bih[128 + c] + bhh[128 + c];
    g.z = bih[256 + c];
    g.w = bhh[256 + c];
    gb4[c] = g;
}

// ---------------- aggregate (type-sorted, branch-free segments) --------------
__global__ __launch_bounds__(256) void k_aggregate_s(const unsigned short* __restrict__ hold,
                                                     const int* __restrict__ rowptr4,
                                                     const int* __restrict__ epack,
                                                     unsigned short* __restrict__ S) {
    int w = threadIdx.x >> 6, l = threadIdx.x & 63;
    int v = blockIdx.x * 4 + w;
    if (v >= N_NODES) return;
    int4v b = *(const int4v*)(rowptr4 + v * 4);
    int b4 = rowptr4[v * 4 + 4];
    const char* hp = (const char*)hold + 4 * l;
    unsigned* Srow = (unsigned*)(S + (size_t)v * 512);
#pragma unroll
    for (int t = 0; t < 4; ++t) {
        int i  = (t == 0) ? b.x : (t == 1) ? b.y : (t == 2) ? b.z : b.w;
        int hi = (t == 0) ? b.y : (t == 1) ? b.z : (t == 2) ? b.w : b4;
        float a0 = 0.f, a1 = 0.f;
        for (; i + 4 <= hi; i += 4) {
            int s0 = epack[i], s1 = epack[i + 1], s2 = epack[i + 2], s3 = epack[i + 3];
            unsigned x0 = *(const unsigned*)(hp + s0);
            unsigned x1 = *(const unsigned*)(hp + s1);
            unsigned x2 = *(const unsigned*)(hp + s2);
            unsigned x3 = *(const unsigned*)(hp + s3);
            a0 += bflo(x0) + bflo(x1) + bflo(x2) + bflo(x3);
            a1 += bfhi(x0) + bfhi(x1) + bfhi(x2) + bfhi(x3);
        }
        if (i + 2 <= hi) {
            int s0 = epack[i], s1 = epack[i + 1];
            unsigned x0 = *(const unsigned*)(hp + s0);
            unsigned x1 = *(const unsigned*)(hp + s1);
            a0 += bflo(x0) + bflo(x1);
            a1 += bfhi(x0) + bfhi(x1);
            i += 2;
        }
        if (i < hi) {
            unsigned x0 = *(const unsigned*)(hp + epack[i]);
            a0 += bflo(x0);
            a1 += bfhi(x0);
        }
        Srow[t * 64 + l] = pk2(a0, a1);
    }
}

// ========== fused a-GEMM + GRU: wave-local LDS relayout, NO barriers ==========
// Block = 4 waves x 16 rows. Phase A: a = S@Wstack + deg-bias -> own 4KB LDS tile
// (C-layout writes, XOR-swizzled). Phase B: read a back as A-frags (same wave,
// lgkmcnt-ordered), h gates GEMM, h update. Grid = ceil(N/64) = 782.
__global__ __launch_bounds__(256) void k_gau(const unsigned short* __restrict__ S,
                                             const unsigned short* __restrict__ hold,
                                             unsigned short* __restrict__ hnew,
                                             const unsigned short* __restrict__ Pmsg,
                                             const unsigned short* __restrict__ Pih,
                                             const unsigned short* __restrict__ Phh,
                                             const int* __restrict__ rowptr4,
                                             const float* __restrict__ bmsg,
                                             const float4* __restrict__ gb4) {
    __shared__ unsigned short At[64 * 128];  // 16 KB; wave w owns rows [w*16, w*16+16)
    int tid = threadIdx.x, w = tid >> 6, l = tid & 63;
    int lr = l & 15, kb = l >> 4;
    int base = blockIdx.x * 64 + w * 16;
    int arow = base + lr; if (arow >= N_NODES) arow = N_NODES - 1;
    char* myrows = (char*)At + (size_t)(w * 16) * 256;

    // ---- phase A: a-GEMM into LDS ----
    {
        const short8* Sr = (const short8*)(S + (size_t)arow * 512);
        short8 af[16];
#pragma unroll
        for (int kc = 0; kc < 16; ++kc) af[kc] = Sr[kc * 4 + kb];
        float dgf[4][4];
#pragma unroll
        for (int j = 0; j < 4; ++j) {
            int row = base + kb * 4 + j; if (row >= N_NODES) row = N_NODES - 1;
            int4v r4 = *(const int4v*)(rowptr4 + row * 4);
            int r5 = rowptr4[row * 4 + 4];
            dgf[j][0] = (float)(r4.y - r4.x);
            dgf[j][1] = (float)(r4.z - r4.y);
            dgf[j][2] = (float)(r4.w - r4.z);
            dgf[j][3] = (float)(r5 - r4.w);
        }
        const short8* Bp = (const short8*)Pmsg;
#pragma unroll
        for (int ntp = 0; ntp < 4; ++ntp) {
            f32x4 acc0 = {0.f, 0.f, 0.f, 0.f}, acc1 = {0.f, 0.f, 0.f, 0.f};
#pragma unroll
            for (int kc = 0; kc < 16; ++kc) {
                short8 b0 = Bp[(size_t)((ntp * 2 + 0) * 16 + kc) * 64 + l];
                short8 b1 = Bp[(size_t)((ntp * 2 + 1) * 16 + kc) * 64 + l];
                acc0 = __builtin_amdgcn_mfma_f32_16x16x32_bf16(af[kc], b0, acc0, 0, 0, 0);
                acc1 = __builtin_amdgcn_mfma_f32_16x16x32_bf16(af[kc], b1, acc1, 0, 0, 0);
            }
#pragma unroll
            for (int half = 0; half < 2; ++half) {
                f32x4 acc = half ? acc1 : acc0;
                int nt = ntp * 2 + half;
                int col = nt * 16 + lr;
                float b0 = bmsg[col], b1 = bmsg[128 + col], b2 = bmsg[256 + col], b3 = bmsg[384 + col];
#pragma unroll
                for (int j = 0; j < 4; ++j) {
                    int rl = kb * 4 + j;  // local row 0..15
                    float av = acc[j] + dgf[j][0] * b0 + dgf[j][1] * b1 +
                               dgf[j][2] * b2 + dgf[j][3] * b3;
                    unsigned byte = (unsigned)(rl * 256 + col * 2) ^ ((unsigned)(rl & 7) << 4);
                    *(unsigned short*)(myrows + byte) = f2bf(av);
                }
            }
        }
    }
    // no __syncthreads: same-wave LDS RAW is ordered via lgkmcnt by the compiler

    // ---- phase B: gates GEMM + h update ----
    {
        const short8* hr = (const short8*)(hold + (size_t)arow * D);
        short8 afh[4], afa[4];
#pragma unroll
        for (int c = 0; c < 4; ++c) {
            afh[c] = hr[c * 4 + kb];
            unsigned byte = (unsigned)(lr * 256 + c * 64 + kb * 16) ^ ((unsigned)(lr & 7) << 4);
            afa[c] = *(const short8*)(myrows + byte);
        }
        const short8* Bi = (const short8*)Pih;
        const short8* Bh = (const short8*)Phh;
#pragma unroll
        for (int nt = 0; nt < 8; ++nt) {
            f32x4 racc = {0.f, 0.f, 0.f, 0.f};
            f32x4 zacc = {0.f, 0.f, 0.f, 0.f};
            f32x4 giacc = {0.f, 0.f, 0.f, 0.f};
            f32x4 ghacc = {0.f, 0.f, 0.f, 0.f};
#pragma unroll
            for (int c = 0; c < 4; ++c) {
                short8 bir = Bi[(size_t)((0 * 8 + nt) * 4 + c) * 64 + l];
                short8 bhr = Bh[(size_t)((0 * 8 + nt) * 4 + c) * 64 + l];
                short8 biz = Bi[(size_t)((1 * 8 + nt) * 4 + c) * 64 + l];
                short8 bhz = Bh[(size_t)((1 * 8 + nt) * 4 + c) * 64 + l];
                short8 bin = Bi[(size_t)((2 * 8 + nt) * 4 + c) * 64 + l];
                short8 bhn = Bh[(size_t)((2 * 8 + nt) * 4 + c) * 64 + l];
                racc = __builtin_amdgcn_mfma_f32_16x16x32_bf16(afa[c], bir, racc, 0, 0, 0);
                racc = __builtin_amdgcn_mfma_f32_16x16x32_bf16(afh[c], bhr, racc, 0, 0, 0);
                zacc = __builtin_amdgcn_mfma_f32_16x16x32_bf16(afa[c], biz, zacc, 0, 0, 0);
                zacc = __builtin_amdgcn_mfma_f32_16x16x32_bf16(afh[c], bhz, zacc, 0, 0, 0);
                giacc = __builtin_amdgcn_mfma_f32_16x16x32_bf16(afa[c], bin, giacc, 0, 0, 0);
                ghacc = __builtin_amdgcn_mfma_f32_16x16x32_bf16(afh[c], bhn, ghacc, 0, 0, 0);
            }
            int col = nt * 16 + lr;
            float4 gb = gb4[col];
#pragma unroll
            for (int j = 0; j < 4; ++j) {
                int row = base + kb * 4 + j;
                if (row < N_NODES) {
                    float rr = fsigmoid(racc[j] + gb.x);
                    float zz = fsigmoid(zacc[j] + gb.y);
                    float nn = ftanh(giacc[j] + gb.z + rr * (ghacc[j] + gb.w));
                    size_t idx = (size_t)row * D + col;
                    float hv = bf2f_u(hold[idx]);
                    hnew[idx] = f2bf((1.f - zz) * nn + zz * hv);
                }
            }
        }
    }
}

// ---------------- pool phase 1: partial row-sums (bf16 h) ----------------
__global__ __launch_bounds__(256) void k_pool1(const unsigned short* __restrict__ hbf,
                                               const int* __restrict__ counts,
                                               float* __restrict__ partial) {
    __shared__ float tmp[256];
    int g = blockIdx.x / POOL_SPLIT;
    int j = blockIdx.x % POOL_SPLIT;
    int t = threadIdx.x;
    int offset = 0;
    for (int i = 0; i < g; ++i) offset += counts[i];
    int cnt = counts[g];
    int d = t & 127, half = t >> 7;
    float acc = 0.f;
    for (int r = 2 * j + half; r < cnt; r += 2 * POOL_SPLIT)
        acc += bf2f_u(hbf[(size_t)(offset + r) * D + d]);
    tmp[t] = acc;
    __syncthreads();
    if (t < D) partial[(size_t)(g * POOL_SPLIT + j) * D + t] = tmp[t] + tmp[t + 128];
}

// ---------------- pool phase 2: combine + MLP + sigmoid ----------------
__global__ __launch_bounds__(256) void k_pool2(const float* __restrict__ partial,
                                               const int* __restrict__ counts,
                                               const float* __restrict__ W1,
                                               const float* __restrict__ b1,
                                               const float* __restrict__ W2,
                                               const float* __restrict__ b2,
                                               float* __restrict__ out) {
    __shared__ float pooled[D];
    __shared__ float xh[HID];
    int g = blockIdx.x;
    int t = threadIdx.x;
    int cnt = counts[g];
    if (t < D) {
        float s = 0.f;
#pragma unroll
        for (int j = 0; j < POOL_SPLIT; ++j)
            s += partial[(size_t)(g * POOL_SPLIT + j) * D + t];
        pooled[t] = s / (float)cnt;
    }
    __syncthreads();
    float x = b1[t];
    for (int k = 0; k < D; ++k) x += pooled[k] * W1[k * HID + t];
    x = fmaxf(x, 0.f);
    xh[t] = x * W2[t];
    __syncthreads();
    for (int s = 128; s > 0; s >>= 1) {
        if (t < s) xh[t] += xh[t + s];
        __syncthreads();
    }
    if (t == 0) out[g] = 1.f / (1.f + __expf(-(xh[0] + b2[0])));
}

extern "C" void kernel_launch(void* const* d_in, const int* in_sizes, int n_in,
                              void* d_out, int out_size, void* d_ws, size_t ws_size,
                              hipStream_t stream) {
    const float* nf   = (const float*)d_in[0];
    const int* esrc   = (const int*)d_in[1];
    const int* edst   = (const int*)d_in[2];
    const int* etyp   = (const int*)d_in[3];
    const int* counts = (const int*)d_in[4];
    const float* Wmsg = (const float*)d_in[5];
    const float* bmsg = (const float*)d_in[6];   // [4][128] flat == [512] concat
    const float* Wih  = (const float*)d_in[7];
    const float* Whh  = (const float*)d_in[8];
    const float* bih  = (const float*)d_in[9];
    const float* bhh  = (const float*)d_in[10];
    const float* W1   = (const float*)d_in[11];
    const float* b1   = (const float*)d_in[12];
    const float* W2   = (const float*)d_in[13];
    const float* b2   = (const float*)d_in[14];
    float* out = (float*)d_out;

    char* ws = (char*)d_ws;
    size_t off = 0;
    auto alloc = [&](size_t bytes) {
        void* p = ws + off;
        off = (off + bytes + 255) & ~(size_t)255;
        return p;
    };
    unsigned short* hbf0 = (unsigned short*)alloc((size_t)N_NODES * D * 2);
    unsigned short* hbf1 = (unsigned short*)alloc((size_t)N_NODES * D * 2);
    unsigned short* S    = (unsigned short*)alloc((size_t)N_NODES * 512 * 2);
    unsigned short* Pmsg = (unsigned short*)alloc(128 * 64 * 8 * 2);
    unsigned short* Pih  = (unsigned short*)alloc(24 * 4 * 64 * 8 * 2);
    unsigned short* Phh  = (unsigned short*)alloc(24 * 4 * 64 * 8 * 2);
    float* gb4 = (float*)alloc(128 * 16);
    int* deg4    = (int*)alloc((size_t)N4 * 4);
    int* rowptr4 = (int*)alloc((size_t)(N4 + 1) * 4);
    int* cursor4 = (int*)alloc((size_t)N4 * 4);
    int* epack   = (int*)alloc((size_t)N_EDGES * 4);
    float* partial = (float*)alloc((size_t)B_GRAPHS * POOL_SPLIT * D * 4);
    int* bsum = (int*)alloc(SCAN_B4 * 4);
    int* bpfx = (int*)alloc(SCAN_B4 * 4);

    hipMemsetAsync(deg4, 0, (size_t)N4 * 4, stream);
    k_init_h<<<(N_NODES * D) / 256, 256, 0, stream>>>(nf, hbf0);
    k_hist<<<N_EDGES / 256, 256, 0, stream>>>(edst, etyp, deg4);
    k_scan1<<<SCAN_B4, 256, 0, stream>>>(deg4, bsum);
    k_scan2<<<1, 1024, 0, stream>>>(bsum, bpfx, rowptr4);
    k_scan3<<<SCAN_B4, 256, 0, stream>>>(deg4, bpfx, rowptr4, cursor4);
    k_fill<<<N_EDGES / 256, 256, 0, stream>>>(esrc, edst, etyp, cursor4, epack);
    k_pack<<<320, 64, 0, stream>>>(Wmsg, Wih, Whh, Pmsg, Pih, Phh);
    k_pack_bias<<<1, 128, 0, stream>>>(bih, bhh, (float4*)gb4);

    int gau_blocks = (N_NODES + 63) / 64;  // 782
    int agg_blocks = (N_NODES + 3) / 4;    // 12500
    for (int s = 0; s < N_STEPS; ++s) {
        const unsigned short* hold = (s & 1) ? hbf1 : hbf0;
        unsigned short* hnew       = (s & 1) ? hbf0 : hbf1;
        k_aggregate_s<<<agg_blocks, 256, 0, stream>>>(hold, rowptr4, epack, S);
        k_gau<<<gau_blocks, 256, 0, stream>>>(S, hold, hnew, Pmsg, Pih, Phh,
                                              rowptr4, bmsg, (const float4*)gb4);
    }
    // after 8 steps (even), final h is in hbf0
    k_pool1<<<B_GRAPHS * POOL_SPLIT, 256, 0, stream>>>(hbf0, counts, partial);
    k_pool2<<<B_GRAPHS, 256, 0, stream>>>(partial, counts, W1, b1, W2, b2, out);
}

// Round 11
// 1083.241 us; speedup vs baseline: 1.0605x; 1.0605x over previous
//
#include <hip/hip_runtime.h>
#include <hip/hip_bf16.h>

#define N_NODES 50000
#define N_EDGES 800000
#define D 128
#define N_ETYPES 4
#define N_STEPS 8
#define B_GRAPHS 50
#define HID 256
#define POOL_SPLIT 16
#define N4 (N_NODES * N_ETYPES)          // 200000 per-(node,type) segments
#define SCAN_B4 ((N4 + 255) / 256)       // 782

typedef __attribute__((ext_vector_type(8))) short short8;
typedef __attribute__((ext_vector_type(4))) float f32x4;
typedef __attribute__((ext_vector_type(4))) unsigned uint4v;
typedef __attribute__((ext_vector_type(4))) int int4v;

static __device__ __forceinline__ unsigned short f2bf(float f) {
    union { float f; unsigned u; } v; v.f = f;
    unsigned r = v.u + 0x7FFF + ((v.u >> 16) & 1);
    return (unsigned short)(r >> 16);
}
static __device__ __forceinline__ unsigned pk2(float a, float b) {
    return (unsigned)f2bf(a) | ((unsigned)f2bf(b) << 16);
}
static __device__ __forceinline__ float bf2f_u(unsigned s) {  // low 16 bits
    union { unsigned u; float f; } v; v.u = s << 16;
    return v.f;
}
static __device__ __forceinline__ float bflo(unsigned x) {
    union { unsigned u; float f; } v; v.u = x << 16;
    return v.f;
}
static __device__ __forceinline__ float bfhi(unsigned x) {
    union { unsigned u; float f; } v; v.u = x & 0xFFFF0000u;
    return v.f;
}
static __device__ __forceinline__ float fsigmoid(float x) {
    return 1.f / (1.f + __expf(-x));
}
static __device__ __forceinline__ float ftanh(float x) {
    return 2.f / (1.f + __expf(-2.f * x)) - 1.f;
}

// ---------------- init: h_bf = bf16(node_features) ----------------
__global__ void k_init_h(const float* __restrict__ nf, unsigned short* __restrict__ hbf) {
    int i = blockIdx.x * blockDim.x + threadIdx.x;
    if (i < N_NODES * D) hbf[i] = f2bf(nf[i]);
}

// ---------------- CSR build over (dst, type) segments ----------------
__global__ void k_hist(const int* __restrict__ dst, const int* __restrict__ et,
                       int* __restrict__ deg4) {
    int e = blockIdx.x * blockDim.x + threadIdx.x;
    if (e < N_EDGES) atomicAdd(&deg4[dst[e] * 4 + et[e]], 1);
}

__global__ __launch_bounds__(256) void k_scan1(const int* __restrict__ deg4,
                                               int* __restrict__ bsum) {
    __shared__ int tmp[256];
    int t = threadIdx.x;
    int i = blockIdx.x * 256 + t;
    tmp[t] = (i < N4) ? deg4[i] : 0;
    __syncthreads();
    for (int s = 128; s > 0; s >>= 1) {
        if (t < s) tmp[t] += tmp[t + s];
        __syncthreads();
    }
    if (t == 0) bsum[blockIdx.x] = tmp[0];
}

__global__ __launch_bounds__(1024) void k_scan2(const int* __restrict__ bsum,
                                                int* __restrict__ bpfx,
                                                int* __restrict__ rowptr4) {
    __shared__ int part[1024];
    int t = threadIdx.x;
    int v = (t < SCAN_B4) ? bsum[t] : 0;
    part[t] = v;
    __syncthreads();
    for (int off = 1; off < 1024; off <<= 1) {
        int u = (t >= off) ? part[t - off] : 0;
        __syncthreads();
        part[t] += u;
        __syncthreads();
    }
    if (t < SCAN_B4) bpfx[t] = part[t] - v;  // exclusive
    if (t == SCAN_B4 - 1) rowptr4[N4] = part[t];  // = N_EDGES
}

__global__ __launch_bounds__(256) void k_scan3(const int* __restrict__ deg4,
                                               const int* __restrict__ bpfx,
                                               int* __restrict__ rowptr4,
                                               int* __restrict__ cursor4) {
    __shared__ int part[256];
    int t = threadIdx.x;
    int i = blockIdx.x * 256 + t;
    int v = (i < N4) ? deg4[i] : 0;
    part[t] = v;
    __syncthreads();
    for (int off = 1; off < 256; off <<= 1) {
        int u = (t >= off) ? part[t - off] : 0;
        __syncthreads();
        part[t] += u;
        __syncthreads();
    }
    if (i < N4) {
        int rp = bpfx[blockIdx.x] + part[t] - v;
        rowptr4[i] = rp;
        cursor4[i] = rp;
    }
}

// epack[slot] = src * 256 (pre-scaled byte offset into h rows)
__global__ void k_fill(const int* __restrict__ src, const int* __restrict__ dst,
                       const int* __restrict__ et, int* __restrict__ cursor4,
                       int* __restrict__ epack) {
    int e = blockIdx.x * blockDim.x + threadIdx.x;
    if (e < N_EDGES) {
        int slot = atomicAdd(&cursor4[dst[e] * 4 + et[e]], 1);
        epack[slot] = src[e] << 8;
    }
}

// ---------------- weight pre-pack into MFMA B-fragment layouts (bf16) --------
__global__ void k_pack(const float* __restrict__ Wmsg, const float* __restrict__ Wih,
                       const float* __restrict__ Whh, unsigned short* __restrict__ Pmsg,
                       unsigned short* __restrict__ Pih, unsigned short* __restrict__ Phh) {
    int bt = blockIdx.x;  // 0..319
    int l = threadIdx.x;  // 0..63
    if (bt < 128) {  // Pmsg frag f = bt ; f = nt*16 + kc
        int nt = bt >> 4, kc = bt & 15;
        int n = nt * 16 + (l & 15);
        unsigned short* out = Pmsg + (((size_t)bt * 64 + l) * 8);
#pragma unroll
        for (int i = 0; i < 8; ++i) {
            int k = kc * 32 + ((l >> 4) << 3) + i;
            out[i] = f2bf(Wmsg[(size_t)(k >> 7) * (D * D) + (k & 127) * D + n]);
        }
        return;
    }
    const float* src;
    unsigned short* dstp;
    int id;
    if (bt < 224) { id = bt - 128; src = Wih; dstp = Pih; }
    else          { id = bt - 224; src = Whh; dstp = Phh; }
    int nt = id >> 2, c = id & 3;
    int n = nt * 16 + (l & 15);
    unsigned short* out = dstp + (((size_t)(nt * 4 + c) * 64 + l) * 8);
#pragma unroll
    for (int i = 0; i < 8; ++i) {
        int k = c * 32 + ((l >> 4) << 3) + i;
        out[i] = f2bf(src[n * D + k]);
    }
}

// ---------------- tiny gate-bias table: gb4[col] = {br, bz, bin, bhn} -------
__global__ void k_pack_bias(const float* __restrict__ bih, const float* __restrict__ bhh,
                            float4* __restrict__ gb4) {
    int c = threadIdx.x;  // 0..127
    float4 g;
    g.x = bih[c] + bhh[c];
    g.y = bih[128 + c] + bhh[128 + c];
    g.z = bih[256 + c];
    g.w = bhh[256 + c];
    gb4[c] = g;
}

// ---------------- aggregate (type-sorted, branch-free segments) --------------
__global__ __launch_bounds__(256) void k_aggregate_s(const unsigned short* __restrict__ hold,
                                                     const int* __restrict__ rowptr4,
                                                     const int* __restrict__ epack,
                                                     unsigned short* __restrict__ S) {
    int w = threadIdx.x >> 6, l = threadIdx.x & 63;
    int v = blockIdx.x * 4 + w;
    int4v b = *(const int4v*)(rowptr4 + v * 4);
    int b4 = rowptr4[v * 4 + 4];
    const char* hp = (const char*)hold + 4 * l;
    unsigned* Srow = (unsigned*)(S + (size_t)v * 512);
#pragma unroll
    for (int t = 0; t < 4; ++t) {
        int i  = (t == 0) ? b.x : (t == 1) ? b.y : (t == 2) ? b.z : b.w;
        int hi = (t == 0) ? b.y : (t == 1) ? b.z : (t == 2) ? b.w : b4;
        float a0 = 0.f, a1 = 0.f;
        for (; i + 4 <= hi; i += 4) {
            int s0 = epack[i], s1 = epack[i + 1], s2 = epack[i + 2], s3 = epack[i + 3];
            unsigned x0 = *(const unsigned*)(hp + s0);
            unsigned x1 = *(const unsigned*)(hp + s1);
            unsigned x2 = *(const unsigned*)(hp + s2);
            unsigned x3 = *(const unsigned*)(hp + s3);
            a0 += bflo(x0) + bflo(x1) + bflo(x2) + bflo(x3);
            a1 += bfhi(x0) + bfhi(x1) + bfhi(x2) + bfhi(x3);
        }
        if (i + 2 <= hi) {
            int s0 = epack[i], s1 = epack[i + 1];
            unsigned x0 = *(const unsigned*)(hp + s0);
            unsigned x1 = *(const unsigned*)(hp + s1);
            a0 += bflo(x0) + bflo(x1);
            a1 += bfhi(x0) + bfhi(x1);
            i += 2;
        }
        if (i < hi) {
            unsigned x0 = *(const unsigned*)(hp + epack[i]);
            a0 += bflo(x0);
            a1 += bfhi(x0);
        }
        Srow[t * 64 + l] = pk2(a0, a1);
    }
}

// ---------------- a-GEMM: 16-row blocks, wave w owns ntiles {2w,2w+1} --------
// Grid = 3125 (exact). Full 64B-line writes per wave. No LDS, no barriers.
__global__ __launch_bounds__(256) void k_gemm_a(const unsigned short* __restrict__ S,
                                                const unsigned short* __restrict__ Pmsg,
                                                const int* __restrict__ rowptr4,
                                                const float* __restrict__ bmsg,
                                                unsigned short* __restrict__ abf) {
    int tid = threadIdx.x, w = tid >> 6, l = tid & 63;
    int lr = l & 15, kb = l >> 4;
    int base = blockIdx.x * 16;
    int arow = base + lr;
    const short8* Sr = (const short8*)(S + (size_t)arow * 512);
    short8 af[16];
#pragma unroll
    for (int kc = 0; kc < 16; ++kc) af[kc] = Sr[kc * 4 + kb];
    float dgf[4][4];
#pragma unroll
    for (int j = 0; j < 4; ++j) {
        int row = base + kb * 4 + j;
        int4v r4 = *(const int4v*)(rowptr4 + row * 4);
        int r5 = rowptr4[row * 4 + 4];
        dgf[j][0] = (float)(r4.y - r4.x);
        dgf[j][1] = (float)(r4.z - r4.y);
        dgf[j][2] = (float)(r4.w - r4.z);
        dgf[j][3] = (float)(r5 - r4.w);
    }
    const short8* Bp = (const short8*)Pmsg;
    int nt0 = 2 * w;
    f32x4 acc0 = {0.f, 0.f, 0.f, 0.f}, acc1 = {0.f, 0.f, 0.f, 0.f};
#pragma unroll
    for (int kc = 0; kc < 16; ++kc) {
        short8 b0 = Bp[(size_t)((nt0 + 0) * 16 + kc) * 64 + l];
        short8 b1 = Bp[(size_t)((nt0 + 1) * 16 + kc) * 64 + l];
        acc0 = __builtin_amdgcn_mfma_f32_16x16x32_bf16(af[kc], b0, acc0, 0, 0, 0);
        acc1 = __builtin_amdgcn_mfma_f32_16x16x32_bf16(af[kc], b1, acc1, 0, 0, 0);
    }
#pragma unroll
    for (int half = 0; half < 2; ++half) {
        f32x4 acc = half ? acc1 : acc0;
        int col = (nt0 + half) * 16 + lr;
        float b0 = bmsg[col], b1 = bmsg[128 + col], b2 = bmsg[256 + col], b3 = bmsg[384 + col];
#pragma unroll
        for (int j = 0; j < 4; ++j) {
            int row = base + kb * 4 + j;
            float bias = dgf[j][0] * b0 + dgf[j][1] * b1 + dgf[j][2] * b2 + dgf[j][3] * b3;
            abf[(size_t)row * D + col] = f2bf(acc[j] + bias);
        }
    }
}

// ---------------- GRU: 16-row blocks, wave w owns ntiles {2w,2w+1} -----------
// Grid = 3125 (exact). Full-line hnew writes per wave. dbuf h. No LDS/barriers.
__global__ __launch_bounds__(256) void k_gru(const unsigned short* __restrict__ abf,
                                             const unsigned short* __restrict__ hold,
                                             unsigned short* __restrict__ hnew,
                                             const unsigned short* __restrict__ Pih,
                                             const unsigned short* __restrict__ Phh,
                                             const float4* __restrict__ gb4) {
    int tid = threadIdx.x, w = tid >> 6, l = tid & 63;
    int lr = l & 15, kb = l >> 4;
    int base = blockIdx.x * 16;
    int arow = base + lr;
    const short8* ar = (const short8*)(abf + (size_t)arow * D);
    const short8* hr = (const short8*)(hold + (size_t)arow * D);
    short8 afa[4], afh[4];
#pragma unroll
    for (int c = 0; c < 4; ++c) { afa[c] = ar[c * 4 + kb]; afh[c] = hr[c * 4 + kb]; }
    const short8* Bi = (const short8*)Pih;  // frag f = (p*8+nt)*4+c
    const short8* Bh = (const short8*)Phh;
    int nt0 = 2 * w;
#pragma unroll
    for (int ntl = 0; ntl < 2; ++ntl) {
        int nt = nt0 + ntl;
        f32x4 racc = {0.f, 0.f, 0.f, 0.f};
        f32x4 zacc = {0.f, 0.f, 0.f, 0.f};
        f32x4 giacc = {0.f, 0.f, 0.f, 0.f};
        f32x4 ghacc = {0.f, 0.f, 0.f, 0.f};
#pragma unroll
        for (int c = 0; c < 4; ++c) {
            short8 bir = Bi[(size_t)((0 * 8 + nt) * 4 + c) * 64 + l];
            short8 bhr = Bh[(size_t)((0 * 8 + nt) * 4 + c) * 64 + l];
            short8 biz = Bi[(size_t)((1 * 8 + nt) * 4 + c) * 64 + l];
            short8 bhz = Bh[(size_t)((1 * 8 + nt) * 4 + c) * 64 + l];
            short8 bin = Bi[(size_t)((2 * 8 + nt) * 4 + c) * 64 + l];
            short8 bhn = Bh[(size_t)((2 * 8 + nt) * 4 + c) * 64 + l];
            racc = __builtin_amdgcn_mfma_f32_16x16x32_bf16(afa[c], bir, racc, 0, 0, 0);
            racc = __builtin_amdgcn_mfma_f32_16x16x32_bf16(afh[c], bhr, racc, 0, 0, 0);
            zacc = __builtin_amdgcn_mfma_f32_16x16x32_bf16(afa[c], biz, zacc, 0, 0, 0);
            zacc = __builtin_amdgcn_mfma_f32_16x16x32_bf16(afh[c], bhz, zacc, 0, 0, 0);
            giacc = __builtin_amdgcn_mfma_f32_16x16x32_bf16(afa[c], bin, giacc, 0, 0, 0);
            ghacc = __builtin_amdgcn_mfma_f32_16x16x32_bf16(afh[c], bhn, ghacc, 0, 0, 0);
        }
        int col = nt * 16 + lr;
        float4 gb = gb4[col];
#pragma unroll
        for (int j = 0; j < 4; ++j) {
            int row = base + kb * 4 + j;
            float rr = fsigmoid(racc[j] + gb.x);
            float zz = fsigmoid(zacc[j] + gb.y);
            float nn = ftanh(giacc[j] + gb.z + rr * (ghacc[j] + gb.w));
            size_t idx = (size_t)row * D + col;
            float hv = bf2f_u(hold[idx]);
            hnew[idx] = f2bf((1.f - zz) * nn + zz * hv);
        }
    }
}

// ---------------- pool phase 1: partial row-sums (bf16 h) ----------------
__global__ __launch_bounds__(256) void k_pool1(const unsigned short* __restrict__ hbf,
                                               const int* __restrict__ counts,
                                               float* __restrict__ partial) {
    __shared__ float tmp[256];
    int g = blockIdx.x / POOL_SPLIT;
    int j = blockIdx.x % POOL_SPLIT;
    int t = threadIdx.x;
    int offset = 0;
    for (int i = 0; i < g; ++i) offset += counts[i];
    int cnt = counts[g];
    int d = t & 127, half = t >> 7;
    float acc = 0.f;
    for (int r = 2 * j + half; r < cnt; r += 2 * POOL_SPLIT)
        acc += bf2f_u(hbf[(size_t)(offset + r) * D + d]);
    tmp[t] = acc;
    __syncthreads();
    if (t < D) partial[(size_t)(g * POOL_SPLIT + j) * D + t] = tmp[t] + tmp[t + 128];
}

// ---------------- pool phase 2: combine + MLP + sigmoid ----------------
__global__ __launch_bounds__(256) void k_pool2(const float* __restrict__ partial,
                                               const int* __restrict__ counts,
                                               const float* __restrict__ W1,
                                               const float* __restrict__ b1,
                                               const float* __restrict__ W2,
                                               const float* __restrict__ b2,
                                               float* __restrict__ out) {
    __shared__ float pooled[D];
    __shared__ float xh[HID];
    int g = blockIdx.x;
    int t = threadIdx.x;
    int cnt = counts[g];
    if (t < D) {
        float s = 0.f;
#pragma unroll
        for (int j = 0; j < POOL_SPLIT; ++j)
            s += partial[(size_t)(g * POOL_SPLIT + j) * D + t];
        pooled[t] = s / (float)cnt;
    }
    __syncthreads();
    float x = b1[t];
    for (int k = 0; k < D; ++k) x += pooled[k] * W1[k * HID + t];
    x = fmaxf(x, 0.f);
    xh[t] = x * W2[t];
    __syncthreads();
    for (int s = 128; s > 0; s >>= 1) {
        if (t < s) xh[t] += xh[t + s];
        __syncthreads();
    }
    if (t == 0) out[g] = 1.f / (1.f + __expf(-(xh[0] + b2[0])));
}

extern "C" void kernel_launch(void* const* d_in, const int* in_sizes, int n_in,
                              void* d_out, int out_size, void* d_ws, size_t ws_size,
                              hipStream_t stream) {
    const float* nf   = (const float*)d_in[0];
    const int* esrc   = (const int*)d_in[1];
    const int* edst   = (const int*)d_in[2];
    const int* etyp   = (const int*)d_in[3];
    const int* counts = (const int*)d_in[4];
    const float* Wmsg = (const float*)d_in[5];
    const float* bmsg = (const float*)d_in[6];   // [4][128] flat == [512] concat
    const float* Wih  = (const float*)d_in[7];
    const float* Whh  = (const float*)d_in[8];
    const float* bih  = (const float*)d_in[9];
    const float* bhh  = (const float*)d_in[10];
    const float* W1   = (const float*)d_in[11];
    const float* b1   = (const float*)d_in[12];
    const float* W2   = (const float*)d_in[13];
    const float* b2   = (const float*)d_in[14];
    float* out = (float*)d_out;

    char* ws = (char*)d_ws;
    size_t off = 0;
    auto alloc = [&](size_t bytes) {
        void* p = ws + off;
        off = (off + bytes + 255) & ~(size_t)255;
        return p;
    };
    unsigned short* hbf0 = (unsigned short*)alloc((size_t)N_NODES * D * 2);
    unsigned short* hbf1 = (unsigned short*)alloc((size_t)N_NODES * D * 2);
    unsigned short* abf  = (unsigned short*)alloc((size_t)N_NODES * D * 2);
    unsigned short* S    = (unsigned short*)alloc((size_t)N_NODES * 512 * 2);
    unsigned short* Pmsg = (unsigned short*)alloc(128 * 64 * 8 * 2);
    unsigned short* Pih  = (unsigned short*)alloc(24 * 4 * 64 * 8 * 2);
    unsigned short* Phh  = (unsigned short*)alloc(24 * 4 * 64 * 8 * 2);
    float* gb4 = (float*)alloc(128 * 16);
    int* deg4    = (int*)alloc((size_t)N4 * 4);
    int* rowptr4 = (int*)alloc((size_t)(N4 + 1) * 4);
    int* cursor4 = (int*)alloc((size_t)N4 * 4);
    int* epack   = (int*)alloc((size_t)N_EDGES * 4);
    float* partial = (float*)alloc((size_t)B_GRAPHS * POOL_SPLIT * D * 4);
    int* bsum = (int*)alloc(SCAN_B4 * 4);
    int* bpfx = (int*)alloc(SCAN_B4 * 4);

    hipMemsetAsync(deg4, 0, (size_t)N4 * 4, stream);
    k_init_h<<<(N_NODES * D) / 256, 256, 0, stream>>>(nf, hbf0);
    k_hist<<<N_EDGES / 256, 256, 0, stream>>>(edst, etyp, deg4);
    k_scan1<<<SCAN_B4, 256, 0, stream>>>(deg4, bsum);
    k_scan2<<<1, 1024, 0, stream>>>(bsum, bpfx, rowptr4);
    k_scan3<<<SCAN_B4, 256, 0, stream>>>(deg4, bpfx, rowptr4, cursor4);
    k_fill<<<N_EDGES / 256, 256, 0, stream>>>(esrc, edst, etyp, cursor4, epack);
    k_pack<<<320, 64, 0, stream>>>(Wmsg, Wih, Whh, Pmsg, Pih, Phh);
    k_pack_bias<<<1, 128, 0, stream>>>(bih, bhh, (float4*)gb4);

    int gemm_blocks = N_NODES / 16;       // 3125 exact
    int agg_blocks  = (N_NODES + 3) / 4;  // 12500
    for (int s = 0; s < N_STEPS; ++s) {
        const unsigned short* hold = (s & 1) ? hbf1 : hbf0;
        unsigned short* hnew       = (s & 1) ? hbf0 : hbf1;
        k_aggregate_s<<<agg_blocks, 256, 0, stream>>>(hold, rowptr4, epack, S);
        k_gemm_a<<<gemm_blocks, 256, 0, stream>>>(S, Pmsg, rowptr4, bmsg, abf);
        k_gru<<<gemm_blocks, 256, 0, stream>>>(abf, hold, hnew, Pih, Phh,
                                               (const float4*)gb4);
    }
    // after 8 steps (even), final h is in hbf0
    k_pool1<<<B_GRAPHS * POOL_SPLIT, 256, 0, stream>>>(hbf0, counts, partial);
    k_pool2<<<B_GRAPHS, 256, 0, stream>>>(partial, counts, W1, b1, W2, b2, out);
}

// Round 12
// 968.876 us; speedup vs baseline: 1.1856x; 1.1180x over previous
//
#include <hip/hip_runtime.h>
#include <hip/hip_bf16.h>

#define N_NODES 50000
#define N_EDGES 800000
#define D 128
#define N_ETYPES 4
#define N_STEPS 8
#define B_GRAPHS 50
#define HID 256
#define POOL_SPLIT 16
#define N4 (N_NODES * N_ETYPES)          // 200000 per-(node,type) segments
#define SCAN_B4 ((N4 + 255) / 256)       // 782

typedef __attribute__((ext_vector_type(8))) short short8;
typedef __attribute__((ext_vector_type(4))) float f32x4;
typedef __attribute__((ext_vector_type(4))) unsigned uint4v;
typedef __attribute__((ext_vector_type(4))) int int4v;

static __device__ __forceinline__ unsigned short f2bf(float f) {
    union { float f; unsigned u; } v; v.f = f;
    unsigned r = v.u + 0x7FFF + ((v.u >> 16) & 1);
    return (unsigned short)(r >> 16);
}
static __device__ __forceinline__ unsigned pk2(float a, float b) {
    return (unsigned)f2bf(a) | ((unsigned)f2bf(b) << 16);
}
static __device__ __forceinline__ float bf2f_u(unsigned s) {  // low 16 bits
    union { unsigned u; float f; } v; v.u = s << 16;
    return v.f;
}
static __device__ __forceinline__ float bflo(unsigned x) {
    union { unsigned u; float f; } v; v.u = x << 16;
    return v.f;
}
static __device__ __forceinline__ float bfhi(unsigned x) {
    union { unsigned u; float f; } v; v.u = x & 0xFFFF0000u;
    return v.f;
}
static __device__ __forceinline__ float fsigmoid(float x) {
    return 1.f / (1.f + __expf(-x));
}
static __device__ __forceinline__ float ftanh(float x) {
    return 2.f / (1.f + __expf(-2.f * x)) - 1.f;
}

// ---------------- init: h_bf = bf16(node_features) ----------------
__global__ void k_init_h(const float* __restrict__ nf, unsigned short* __restrict__ hbf) {
    int i = blockIdx.x * blockDim.x + threadIdx.x;
    if (i < N_NODES * D) hbf[i] = f2bf(nf[i]);
}

// ---------------- CSR build over (dst, type) segments ----------------
__global__ void k_hist(const int* __restrict__ dst, const int* __restrict__ et,
                       int* __restrict__ deg4) {
    int e = blockIdx.x * blockDim.x + threadIdx.x;
    if (e < N_EDGES) atomicAdd(&deg4[dst[e] * 4 + et[e]], 1);
}

__global__ __launch_bounds__(256) void k_scan1(const int* __restrict__ deg4,
                                               int* __restrict__ bsum) {
    __shared__ int tmp[256];
    int t = threadIdx.x;
    int i = blockIdx.x * 256 + t;
    tmp[t] = (i < N4) ? deg4[i] : 0;
    __syncthreads();
    for (int s = 128; s > 0; s >>= 1) {
        if (t < s) tmp[t] += tmp[t + s];
        __syncthreads();
    }
    if (t == 0) bsum[blockIdx.x] = tmp[0];
}

__global__ __launch_bounds__(1024) void k_scan2(const int* __restrict__ bsum,
                                                int* __restrict__ bpfx,
                                                int* __restrict__ rowptr4) {
    __shared__ int part[1024];
    int t = threadIdx.x;
    int v = (t < SCAN_B4) ? bsum[t] : 0;
    part[t] = v;
    __syncthreads();
    for (int off = 1; off < 1024; off <<= 1) {
        int u = (t >= off) ? part[t - off] : 0;
        __syncthreads();
        part[t] += u;
        __syncthreads();
    }
    if (t < SCAN_B4) bpfx[t] = part[t] - v;  // exclusive
    if (t == SCAN_B4 - 1) rowptr4[N4] = part[t];  // = N_EDGES
}

__global__ __launch_bounds__(256) void k_scan3(const int* __restrict__ deg4,
                                               const int* __restrict__ bpfx,
                                               int* __restrict__ rowptr4,
                                               int* __restrict__ cursor4) {
    __shared__ int part[256];
    int t = threadIdx.x;
    int i = blockIdx.x * 256 + t;
    int v = (i < N4) ? deg4[i] : 0;
    part[t] = v;
    __syncthreads();
    for (int off = 1; off < 256; off <<= 1) {
        int u = (t >= off) ? part[t - off] : 0;
        __syncthreads();
        part[t] += u;
        __syncthreads();
    }
    if (i < N4) {
        int rp = bpfx[blockIdx.x] + part[t] - v;
        rowptr4[i] = rp;
        cursor4[i] = rp;
    }
}

// epack[slot] = src * 256 (pre-scaled byte offset into h rows)
__global__ void k_fill(const int* __restrict__ src, const int* __restrict__ dst,
                       const int* __restrict__ et, int* __restrict__ cursor4,
                       int* __restrict__ epack) {
    int e = blockIdx.x * blockDim.x + threadIdx.x;
    if (e < N_EDGES) {
        int slot = atomicAdd(&cursor4[dst[e] * 4 + et[e]], 1);
        epack[slot] = src[e] << 8;
    }
}

// ---------------- weight pre-pack into MFMA B-fragment layouts (bf16) --------
__global__ void k_pack(const float* __restrict__ Wmsg, const float* __restrict__ Wih,
                       const float* __restrict__ Whh, unsigned short* __restrict__ Pmsg,
                       unsigned short* __restrict__ Pih, unsigned short* __restrict__ Phh) {
    int bt = blockIdx.x;  // 0..319
    int l = threadIdx.x;  // 0..63
    if (bt < 128) {  // Pmsg frag f = bt ; f = nt*16 + kc
        int nt = bt >> 4, kc = bt & 15;
        int n = nt * 16 + (l & 15);
        unsigned short* out = Pmsg + (((size_t)bt * 64 + l) * 8);
#pragma unroll
        for (int i = 0; i < 8; ++i) {
            int k = kc * 32 + ((l >> 4) << 3) + i;
            out[i] = f2bf(Wmsg[(size_t)(k >> 7) * (D * D) + (k & 127) * D + n]);
        }
        return;
    }
    const float* src;
    unsigned short* dstp;
    int id;
    if (bt < 224) { id = bt - 128; src = Wih; dstp = Pih; }
    else          { id = bt - 224; src = Whh; dstp = Phh; }
    int nt = id >> 2, c = id & 3;
    int n = nt * 16 + (l & 15);
    unsigned short* out = dstp + (((size_t)(nt * 4 + c) * 64 + l) * 8);
#pragma unroll
    for (int i = 0; i < 8; ++i) {
        int k = c * 32 + ((l >> 4) << 3) + i;
        out[i] = f2bf(src[n * D + k]);
    }
}

// ---------------- tiny gate-bias table: gb4[col] = {br, bz, bin, bhn} -------
__global__ void k_pack_bias(const float* __restrict__ bih, const float* __restrict__ bhh,
                            float4* __restrict__ gb4) {
    int c = threadIdx.x;  // 0..127
    float4 g;
    g.x = bih[c] + bhh[c];
    g.y = bih[128 + c] + bhh[128 + c];
    g.z = bih[256 + c];
    g.w = bhh[256 + c];
    gb4[c] = g;
}

// ------- aggregate: 4 type-segments interleaved for ILP (latency-bound) -----
// one wave per node; lane l covers d = 2l, 2l+1. All control is wave-uniform.
__global__ __launch_bounds__(256) void k_aggregate_s(const unsigned short* __restrict__ hold,
                                                     const int* __restrict__ rowptr4,
                                                     const int* __restrict__ epack,
                                                     unsigned short* __restrict__ S) {
    int w = threadIdx.x >> 6, l = threadIdx.x & 63;
    int v = blockIdx.x * 4 + w;
    int4v b = *(const int4v*)(rowptr4 + v * 4);
    int b4 = rowptr4[v * 4 + 4];
    const char* hp = (const char*)hold + 4 * l;
    float a00 = 0.f, a01 = 0.f, a10 = 0.f, a11 = 0.f;
    float a20 = 0.f, a21 = 0.f, a30 = 0.f, a31 = 0.f;
    int i0 = b.x, i1 = b.y, i2 = b.z, i3 = b.w;
    const int h0 = b.y, h1 = b.z, h2 = b.w, h3 = b4;
    // 4-way interleaved peel: 4 independent loads in flight per round
    int rounds = min(min(h0 - i0, h1 - i1), min(h2 - i2, h3 - i3));
#pragma unroll 2
    for (int r = 0; r < rounds; ++r) {
        unsigned x0 = *(const unsigned*)(hp + epack[i0 + r]);
        unsigned x1 = *(const unsigned*)(hp + epack[i1 + r]);
        unsigned x2 = *(const unsigned*)(hp + epack[i2 + r]);
        unsigned x3 = *(const unsigned*)(hp + epack[i3 + r]);
        a00 += bflo(x0); a01 += bfhi(x0);
        a10 += bflo(x1); a11 += bfhi(x1);
        a20 += bflo(x2); a21 += bfhi(x2);
        a30 += bflo(x3); a31 += bfhi(x3);
    }
    i0 += rounds; i1 += rounds; i2 += rounds; i3 += rounds;
    // pairwise peels: 2 loads in flight
    int r01 = min(h0 - i0, h1 - i1);
#pragma unroll 2
    for (int r = 0; r < r01; ++r) {
        unsigned x0 = *(const unsigned*)(hp + epack[i0 + r]);
        unsigned x1 = *(const unsigned*)(hp + epack[i1 + r]);
        a00 += bflo(x0); a01 += bfhi(x0);
        a10 += bflo(x1); a11 += bfhi(x1);
    }
    i0 += r01; i1 += r01;
    int r23 = min(h2 - i2, h3 - i3);
#pragma unroll 2
    for (int r = 0; r < r23; ++r) {
        unsigned x2 = *(const unsigned*)(hp + epack[i2 + r]);
        unsigned x3 = *(const unsigned*)(hp + epack[i3 + r]);
        a20 += bflo(x2); a21 += bfhi(x2);
        a30 += bflo(x3); a31 += bfhi(x3);
    }
    i2 += r23; i3 += r23;
    // serial tails (only one of each pair is non-empty)
#pragma unroll 2
    for (; i0 < h0; ++i0) { unsigned x = *(const unsigned*)(hp + epack[i0]); a00 += bflo(x); a01 += bfhi(x); }
#pragma unroll 2
    for (; i1 < h1; ++i1) { unsigned x = *(const unsigned*)(hp + epack[i1]); a10 += bflo(x); a11 += bfhi(x); }
#pragma unroll 2
    for (; i2 < h2; ++i2) { unsigned x = *(const unsigned*)(hp + epack[i2]); a20 += bflo(x); a21 += bfhi(x); }
#pragma unroll 2
    for (; i3 < h3; ++i3) { unsigned x = *(const unsigned*)(hp + epack[i3]); a30 += bflo(x); a31 += bfhi(x); }
    unsigned* Srow = (unsigned*)(S + (size_t)v * 512);
    Srow[l]       = pk2(a00, a01);
    Srow[64 + l]  = pk2(a10, a11);
    Srow[128 + l] = pk2(a20, a21);
    Srow[192 + l] = pk2(a30, a31);
}

// ---------------- a-GEMM: 64-row blocks, wave = 16 distinct rows x 8 ntiles --
// Grid 782. S read 1x, full-line writes. No LDS, no barriers.
__global__ __launch_bounds__(256) void k_gemm_a(const unsigned short* __restrict__ S,
                                                const unsigned short* __restrict__ Pmsg,
                                                const int* __restrict__ rowptr4,
                                                const float* __restrict__ bmsg,
                                                unsigned short* __restrict__ abf) {
    int tid = threadIdx.x, w = tid >> 6, l = tid & 63;
    int lr = l & 15, kb = l >> 4;
    int base = blockIdx.x * 64 + w * 16;
    int arow = base + lr; if (arow >= N_NODES) arow = N_NODES - 1;
    const short8* Sr = (const short8*)(S + (size_t)arow * 512);
    short8 af[16];
#pragma unroll
    for (int kc = 0; kc < 16; ++kc) af[kc] = Sr[kc * 4 + kb];
    float dgf[4][4];
#pragma unroll
    for (int j = 0; j < 4; ++j) {
        int row = base + kb * 4 + j; if (row >= N_NODES) row = N_NODES - 1;
        int4v r4 = *(const int4v*)(rowptr4 + row * 4);
        int r5 = rowptr4[row * 4 + 4];
        dgf[j][0] = (float)(r4.y - r4.x);
        dgf[j][1] = (float)(r4.z - r4.y);
        dgf[j][2] = (float)(r4.w - r4.z);
        dgf[j][3] = (float)(r5 - r4.w);
    }
    const short8* Bp = (const short8*)Pmsg;
#pragma unroll
    for (int ntp = 0; ntp < 4; ++ntp) {
        f32x4 acc0 = {0.f, 0.f, 0.f, 0.f}, acc1 = {0.f, 0.f, 0.f, 0.f};
#pragma unroll
        for (int kc = 0; kc < 16; ++kc) {
            short8 b0 = Bp[(size_t)((ntp * 2 + 0) * 16 + kc) * 64 + l];
            short8 b1 = Bp[(size_t)((ntp * 2 + 1) * 16 + kc) * 64 + l];
            acc0 = __builtin_amdgcn_mfma_f32_16x16x32_bf16(af[kc], b0, acc0, 0, 0, 0);
            acc1 = __builtin_amdgcn_mfma_f32_16x16x32_bf16(af[kc], b1, acc1, 0, 0, 0);
        }
#pragma unroll
        for (int half = 0; half < 2; ++half) {
            f32x4 acc = half ? acc1 : acc0;
            int col = (ntp * 2 + half) * 16 + lr;
            float b0 = bmsg[col], b1 = bmsg[128 + col], b2 = bmsg[256 + col], b3 = bmsg[384 + col];
#pragma unroll
            for (int j = 0; j < 4; ++j) {
                int row = base + kb * 4 + j;
                if (row < N_NODES) {
                    float bias = dgf[j][0] * b0 + dgf[j][1] * b1 + dgf[j][2] * b2 + dgf[j][3] * b3;
                    abf[(size_t)row * D + col] = f2bf(acc[j] + bias);
                }
            }
        }
    }
}

// ---------------- GRU: 16-row blocks, wave w owns ntiles {2w,2w+1} -----------
// Grid = 3125 (exact). Full-line hnew writes per wave. dbuf h. No LDS/barriers.
__global__ __launch_bounds__(256) void k_gru(const unsigned short* __restrict__ abf,
                                             const unsigned short* __restrict__ hold,
                                             unsigned short* __restrict__ hnew,
                                             const unsigned short* __restrict__ Pih,
                                             const unsigned short* __restrict__ Phh,
                                             const float4* __restrict__ gb4) {
    int tid = threadIdx.x, w = tid >> 6, l = tid & 63;
    int lr = l & 15, kb = l >> 4;
    int base = blockIdx.x * 16;
    int arow = base + lr;
    const short8* ar = (const short8*)(abf + (size_t)arow * D);
    const short8* hr = (const short8*)(hold + (size_t)arow * D);
    short8 afa[4], afh[4];
#pragma unroll
    for (int c = 0; c < 4; ++c) { afa[c] = ar[c * 4 + kb]; afh[c] = hr[c * 4 + kb]; }
    const short8* Bi = (const short8*)Pih;  // frag f = (p*8+nt)*4+c
    const short8* Bh = (const short8*)Phh;
    int nt0 = 2 * w;
#pragma unroll
    for (int ntl = 0; ntl < 2; ++ntl) {
        int nt = nt0 + ntl;
        f32x4 racc = {0.f, 0.f, 0.f, 0.f};
        f32x4 zacc = {0.f, 0.f, 0.f, 0.f};
        f32x4 giacc = {0.f, 0.f, 0.f, 0.f};
        f32x4 ghacc = {0.f, 0.f, 0.f, 0.f};
#pragma unroll
        for (int c = 0; c < 4; ++c) {
            short8 bir = Bi[(size_t)((0 * 8 + nt) * 4 + c) * 64 + l];
            short8 bhr = Bh[(size_t)((0 * 8 + nt) * 4 + c) * 64 + l];
            short8 biz = Bi[(size_t)((1 * 8 + nt) * 4 + c) * 64 + l];
            short8 bhz = Bh[(size_t)((1 * 8 + nt) * 4 + c) * 64 + l];
            short8 bin = Bi[(size_t)((2 * 8 + nt) * 4 + c) * 64 + l];
            short8 bhn = Bh[(size_t)((2 * 8 + nt) * 4 + c) * 64 + l];
            racc = __builtin_amdgcn_mfma_f32_16x16x32_bf16(afa[c], bir, racc, 0, 0, 0);
            racc = __builtin_amdgcn_mfma_f32_16x16x32_bf16(afh[c], bhr, racc, 0, 0, 0);
            zacc = __builtin_amdgcn_mfma_f32_16x16x32_bf16(afa[c], biz, zacc, 0, 0, 0);
            zacc = __builtin_amdgcn_mfma_f32_16x16x32_bf16(afh[c], bhz, zacc, 0, 0, 0);
            giacc = __builtin_amdgcn_mfma_f32_16x16x32_bf16(afa[c], bin, giacc, 0, 0, 0);
            ghacc = __builtin_amdgcn_mfma_f32_16x16x32_bf16(afh[c], bhn, ghacc, 0, 0, 0);
        }
        int col = nt * 16 + lr;
        float4 gb = gb4[col];
#pragma unroll
        for (int j = 0; j < 4; ++j) {
            int row = base + kb * 4 + j;
            float rr = fsigmoid(racc[j] + gb.x);
            float zz = fsigmoid(zacc[j] + gb.y);
            float nn = ftanh(giacc[j] + gb.z + rr * (ghacc[j] + gb.w));
            size_t idx = (size_t)row * D + col;
            float hv = bf2f_u(hold[idx]);
            hnew[idx] = f2bf((1.f - zz) * nn + zz * hv);
        }
    }
}

// ---------------- pool phase 1: partial row-sums (bf16 h) ----------------
__global__ __launch_bounds__(256) void k_pool1(const unsigned short* __restrict__ hbf,
                                               const int* __restrict__ counts,
                                               float* __restrict__ partial) {
    __shared__ float tmp[256];
    int g = blockIdx.x / POOL_SPLIT;
    int j = blockIdx.x % POOL_SPLIT;
    int t = threadIdx.x;
    int offset = 0;
    for (int i = 0; i < g; ++i) offset += counts[i];
    int cnt = counts[g];
    int d = t & 127, half = t >> 7;
    float acc = 0.f;
    for (int r = 2 * j + half; r < cnt; r += 2 * POOL_SPLIT)
        acc += bf2f_u(hbf[(size_t)(offset + r) * D + d]);
    tmp[t] = acc;
    __syncthreads();
    if (t < D) partial[(size_t)(g * POOL_SPLIT + j) * D + t] = tmp[t] + tmp[t + 128];
}

// ---------------- pool phase 2: combine + MLP + sigmoid ----------------
__global__ __launch_bounds__(256) void k_pool2(const float* __restrict__ partial,
                                               const int* __restrict__ counts,
                                               const float* __restrict__ W1,
                                               const float* __restrict__ b1,
                                               const float* __restrict__ W2,
                                               const float* __restrict__ b2,
                                               float* __restrict__ out) {
    __shared__ float pooled[D];
    __shared__ float xh[HID];
    int g = blockIdx.x;
    int t = threadIdx.x;
    int cnt = counts[g];
    if (t < D) {
        float s = 0.f;
#pragma unroll
        for (int j = 0; j < POOL_SPLIT; ++j)
            s += partial[(size_t)(g * POOL_SPLIT + j) * D + t];
        pooled[t] = s / (float)cnt;
    }
    __syncthreads();
    float x = b1[t];
    for (int k = 0; k < D; ++k) x += pooled[k] * W1[k * HID + t];
    x = fmaxf(x, 0.f);
    xh[t] = x * W2[t];
    __syncthreads();
    for (int s = 128; s > 0; s >>= 1) {
        if (t < s) xh[t] += xh[t + s];
        __syncthreads();
    }
    if (t == 0) out[g] = 1.f / (1.f + __expf(-(xh[0] + b2[0])));
}

extern "C" void kernel_launch(void* const* d_in, const int* in_sizes, int n_in,
                              void* d_out, int out_size, void* d_ws, size_t ws_size,
                              hipStream_t stream) {
    const float* nf   = (const float*)d_in[0];
    const int* esrc   = (const int*)d_in[1];
    const int* edst   = (const int*)d_in[2];
    const int* etyp   = (const int*)d_in[3];
    const int* counts = (const int*)d_in[4];
    const float* Wmsg = (const float*)d_in[5];
    const float* bmsg = (const float*)d_in[6];   // [4][128] flat == [512] concat
    const float* Wih  = (const float*)d_in[7];
    const float* Whh  = (const float*)d_in[8];
    const float* bih  = (const float*)d_in[9];
    const float* bhh  = (const float*)d_in[10];
    const float* W1   = (const float*)d_in[11];
    const float* b1   = (const float*)d_in[12];
    const float* W2   = (const float*)d_in[13];
    const float* b2   = (const float*)d_in[14];
    float* out = (float*)d_out;

    char* ws = (char*)d_ws;
    size_t off = 0;
    auto alloc = [&](size_t bytes) {
        void* p = ws + off;
        off = (off + bytes + 255) & ~(size_t)255;
        return p;
    };
    unsigned short* hbf0 = (unsigned short*)alloc((size_t)N_NODES * D * 2);
    unsigned short* hbf1 = (unsigned short*)alloc((size_t)N_NODES * D * 2);
    unsigned short* abf  = (unsigned short*)alloc((size_t)N_NODES * D * 2);
    unsigned short* S    = (unsigned short*)alloc((size_t)N_NODES * 512 * 2);
    unsigned short* Pmsg = (unsigned short*)alloc(128 * 64 * 8 * 2);
    unsigned short* Pih  = (unsigned short*)alloc(24 * 4 * 64 * 8 * 2);
    unsigned short* Phh  = (unsigned short*)alloc(24 * 4 * 64 * 8 * 2);
    float* gb4 = (float*)alloc(128 * 16);
    int* deg4    = (int*)alloc((size_t)N4 * 4);
    int* rowptr4 = (int*)alloc((size_t)(N4 + 1) * 4);
    int* cursor4 = (int*)alloc((size_t)N4 * 4);
    int* epack   = (int*)alloc((size_t)N_EDGES * 4);
    float* partial = (float*)alloc((size_t)B_GRAPHS * POOL_SPLIT * D * 4);
    int* bsum = (int*)alloc(SCAN_B4 * 4);
    int* bpfx = (int*)alloc(SCAN_B4 * 4);

    hipMemsetAsync(deg4, 0, (size_t)N4 * 4, stream);
    k_init_h<<<(N_NODES * D) / 256, 256, 0, stream>>>(nf, hbf0);
    k_hist<<<N_EDGES / 256, 256, 0, stream>>>(edst, etyp, deg4);
    k_scan1<<<SCAN_B4, 256, 0, stream>>>(deg4, bsum);
    k_scan2<<<1, 1024, 0, stream>>>(bsum, bpfx, rowptr4);
    k_scan3<<<SCAN_B4, 256, 0, stream>>>(deg4, bpfx, rowptr4, cursor4);
    k_fill<<<N_EDGES / 256, 256, 0, stream>>>(esrc, edst, etyp, cursor4, epack);
    k_pack<<<320, 64, 0, stream>>>(Wmsg, Wih, Whh, Pmsg, Pih, Phh);
    k_pack_bias<<<1, 128, 0, stream>>>(bih, bhh, (float4*)gb4);

    int ga_blocks  = (N_NODES + 63) / 64;  // 782
    int gru_blocks = N_NODES / 16;         // 3125 exact
    int agg_blocks = N_NODES / 4;          // 12500 exact
    for (int s = 0; s < N_STEPS; ++s) {
        const unsigned short* hold = (s & 1) ? hbf1 : hbf0;
        unsigned short* hnew       = (s & 1) ? hbf0 : hbf1;
        k_aggregate_s<<<agg_blocks, 256, 0, stream>>>(hold, rowptr4, epack, S);
        k_gemm_a<<<ga_blocks, 256, 0, stream>>>(S, Pmsg, rowptr4, bmsg, abf);
        k_gru<<<gru_blocks, 256, 0, stream>>>(abf, hold, hnew, Pih, Phh,
                                              (const float4*)gb4);
    }
    // after 8 steps (even), final h is in hbf0
    k_pool1<<<B_GRAPHS * POOL_SPLIT, 256, 0, stream>>>(hbf0, counts, partial);
    k_pool2<<<B_GRAPHS, 256, 0, stream>>>(partial, counts, W1, b1, W2, b2, out);
}